// Round 4
// baseline (1279.151 us; speedup 1.0000x reference)
//
#include <hip/hip_runtime.h>

#define EPSF 1e-8f

constexpr int NB = 64;   // batch
constexpr int NO = 64;   // out capsules
constexpr int NI = 1152; // in capsules
constexpr int ND = 16;   // pose dims

// fp32 row loader ------------------------------------------------------------
__device__ __forceinline__ void loadrow16f(const float* __restrict__ base,
                                           size_t elem, float* f){
  const float4* p = (const float4*)(base + elem);
  float4 x0=p[0], x1=p[1], x2=p[2], x3=p[3];
  f[0]=x0.x; f[1]=x0.y; f[2]=x0.z; f[3]=x0.w;
  f[4]=x1.x; f[5]=x1.y; f[6]=x1.z; f[7]=x1.w;
  f[8]=x2.x; f[9]=x2.y; f[10]=x2.z; f[11]=x2.w;
  f[12]=x3.x; f[13]=x3.y; f[14]=x3.z; f[15]=x3.w;
}

// ---------------- kernel 1: a_i = ||u + eps||, asum[b] = sum_i a_i ----------
__global__ __launch_bounds__(256) void k_ai(const float* __restrict__ u,
                                            float* __restrict__ a_i,
                                            float* __restrict__ asum)
{
  const int b = blockIdx.x;
  const int t = threadIdx.x;
  float acc = 0.f;
  for (int i = t; i < NI; i += 256){
    float f[16];
    loadrow16f(u, ((size_t)b*NI + i)*ND, f);
    float s = 0.f;
    #pragma unroll
    for (int d=0; d<16; ++d){ float x = f[d] + EPSF; s += x*x; }
    float a = sqrtf(s);
    a_i[b*NI + i] = a;
    acc += a;
  }
  #pragma unroll
  for (int off=32; off; off>>=1) acc += __shfl_down(acc, off);
  __shared__ float r[4];
  if ((t & 63) == 0) r[t >> 6] = acc;
  __syncthreads();
  if (t == 0) asum[b] = r[0]+r[1]+r[2]+r[3];
}

// ---------------- kernel 2: iter-0 m-step (uniform rr = 1/64) ---------------
// grid (o, bgroup of 8 b). thread = (bl 0..7, il 0..31).
__global__ __launch_bounds__(256) void k_mstep0(
    const float* __restrict__ u, const float* __restrict__ W,
    const float* __restrict__ beta_a, const float* __restrict__ beta_u,
    const float* __restrict__ bias,
    const float* __restrict__ a_i, const float* __restrict__ asum,
    float* __restrict__ mean0, float* __restrict__ i2v0, float* __restrict__ c0)
{
  const int o  = blockIdx.x;
  const int bg = blockIdx.y;
  const int t  = threadIdx.x;
  const int bl = t >> 5;
  const int il = t & 31;
  const int b  = bg*8 + bl;

  float bs[16];
  loadrow16f(bias, (size_t)o*ND, bs);

  float S1[16], S2[16];
  #pragma unroll
  for (int e=0;e<16;++e){ S1[e]=0.f; S2[e]=0.f; }

  for (int i = il; i < NI; i += 32){
    float uf[16];
    loadrow16f(u, ((size_t)b*NI + i)*ND, uf);
    float wgt = a_i[b*NI + i];
    const size_t wbase = ((size_t)o*NI + i)*(ND*ND);
    #pragma unroll
    for (int e=0;e<16;++e){
      float wf[16];
      loadrow16f(W, wbase + (size_t)e*16, wf);
      float d0=0.f,d1=0.f,d2=0.f,d3=0.f;
      #pragma unroll
      for (int d=0; d<16; d+=4){
        d0 += uf[d+0]*wf[d+0]; d1 += uf[d+1]*wf[d+1];
        d2 += uf[d+2]*wf[d+2]; d3 += uf[d+3]*wf[d+3];
      }
      float V = ((d0+d1)+(d2+d3)) + EPSF + bs[e];
      float wv = wgt*V;
      S1[e] += wv;
      S2[e] += wv*V;
    }
  }
  #pragma unroll
  for (int e=0;e<16;++e){
    #pragma unroll
    for (int off=16; off; off>>=1){
      S1[e] += __shfl_down(S1[e], off, 32);
      S2[e] += __shfl_down(S2[e], off, 32);
    }
  }
  if (il == 0){
    const float rrsum = asum[b] * (1.f/64.f);
    float cost = 0.f, prod = 1.f;
    const float buv = beta_u[o];
    const size_t mbase = ((size_t)b*NO + o)*ND;
    #pragma unroll
    for (int e=0;e<16;++e){
      float T1 = S1[e]*(1.f/64.f);
      float T2 = S2[e]*(1.f/64.f);
      float m  = T1/(rrsum + EPSF);
      float var = (T2 - 2.f*m*T1 + m*m*rrsum)/(rrsum + EPSF) + 1e-4f;
      mean0[mbase+e] = m;
      i2v0[mbase+e]  = 1.f/(2.f*var + EPSF);
      cost += buv + __logf(var);
      prod *= var;
    }
    cost *= rrsum;
    float x  = 5.0e-4f*(beta_a[o] - cost);   // inv_temp iter0 = 0.01*(1-0.95)
    float aj = 1.f/(1.f + __expf(-x));
    float p1 = sqrtf(6.2831853071795864f*prod + EPSF);
    c0[(size_t)b*NO + o] = aj/(p1 + EPSF);
  }
}

// ---------------- kernel 3: fused e-step + iter-1 m-step moment sums --------
// grid (bgroup of 4 b, chunk c of CH=gridDim.y). thread = (wave bl = b, lane = o).
__global__ __launch_bounds__(256) void k_estep1(
    const float* __restrict__ u, const float* __restrict__ W,
    const float* __restrict__ bias,
    const float* __restrict__ a_i,
    const float* __restrict__ mean0, const float* __restrict__ i2v0,
    const float* __restrict__ c0,
    float* __restrict__ S1p, float* __restrict__ S2p, float* __restrict__ Wsp)
{
  const int CH  = gridDim.y;
  const int CHI = NI / CH;
  const int bg = blockIdx.x;
  const int c  = blockIdx.y;
  const int t  = threadIdx.x;
  const int o  = t & 63;
  const int bl = t >> 6;
  const int b  = bg*4 + bl;

  float bs[16];
  loadrow16f(bias, (size_t)o*ND, bs);
  float mr[16], ir[16];
  { const size_t mbase = ((size_t)b*NO + o)*ND;
    #pragma unroll
    for (int e=0;e<16;++e){ mr[e]=mean0[mbase+e]; ir[e]=i2v0[mbase+e]; } }
  const float c0r = c0[(size_t)b*NO + o];

  float S1[16], S2[16]; float wsum = 0.f;
  #pragma unroll
  for (int e=0;e<16;++e){ S1[e]=0.f; S2[e]=0.f; }

  for (int k=0; k<CHI; ++k){
    const int i = c*CHI + k;
    float uf[16];
    loadrow16f(u, ((size_t)b*NI + i)*ND, uf);
    const float av = a_i[b*NI + i];
    const size_t wbase = ((size_t)o*NI + i)*(ND*ND);
    float V[16]; float la = 0.f;
    #pragma unroll
    for (int e=0;e<16;++e){
      float wf[16];
      loadrow16f(W, wbase + (size_t)e*16, wf);
      float d0=0.f,d1=0.f,d2=0.f,d3=0.f;
      #pragma unroll
      for (int d=0; d<16; d+=4){
        d0 += uf[d+0]*wf[d+0]; d1 += uf[d+1]*wf[d+1];
        d2 += uf[d+2]*wf[d+2]; d3 += uf[d+3]*wf[d+3];
      }
      float Ve = ((d0+d1)+(d2+d3)) + EPSF + bs[e];
      V[e] = Ve;
      float df = Ve - mr[e];
      la += df*df*ir[e];
    }
    float ap = c0r*__expf(-la);
    float dsum = ap;
    #pragma unroll
    for (int off=32; off; off>>=1) dsum += __shfl_xor(dsum, off);
    float rr = ap/(dsum + EPSF);
    float wg = rr*av;
    wsum += wg;
    #pragma unroll
    for (int e=0;e<16;++e){ float tv = wg*V[e]; S1[e]+=tv; S2[e]+=tv*V[e]; }
  }
  const size_t base = (((size_t)b*CH + c)*NO + o);
  #pragma unroll
  for (int e=0;e<16;++e){ S1p[base*ND+e]=S1[e]; S2p[base*ND+e]=S2[e]; }
  Wsp[base] = wsum;
}

// ---------------- kernel 4: reduce partials, finalize output (fp32!) --------
__global__ __launch_bounds__(64) void k_final(
    const float* __restrict__ beta_a, const float* __restrict__ beta_u,
    const float* __restrict__ S1p, const float* __restrict__ S2p,
    const float* __restrict__ Wsp, const int CH,
    float* __restrict__ out)
{
  const int bo = blockIdx.x;
  const int b = bo >> 6, o = bo & 63;
  const int t = threadIdx.x;
  __shared__ float S1s[16], S2s[16], Wss;
  __shared__ float mean_s[16], ct_s[16], nt_s[16];
  __shared__ float scale_s;
  if (t < 16){
    float s = 0.f;
    for (int c=0;c<CH;++c) s += S1p[((((size_t)b*CH)+c)*NO + o)*ND + t];
    S1s[t] = s;
  } else if (t < 32){
    const int e = t - 16; float s = 0.f;
    for (int c=0;c<CH;++c) s += S2p[((((size_t)b*CH)+c)*NO + o)*ND + e];
    S2s[e] = s;
  } else if (t == 32){
    float s = 0.f;
    for (int c=0;c<CH;++c) s += Wsp[(((size_t)b*CH)+c)*NO + o];
    Wss = s;
  }
  __syncthreads();
  const float Wsum = Wss;
  if (t < 16){
    float S1 = S1s[t], S2 = S2s[t];
    float m = S1/(Wsum + EPSF);
    float var = (S2 - 2.f*m*S1 + m*m*Wsum)/(Wsum + EPSF) + 1e-4f;
    mean_s[t] = m;
    ct_s[t] = beta_u[o] + __logf(var);
    float me = m + EPSF;
    nt_s[t] = me*me;
  }
  __syncthreads();
  if (t == 0){
    float cost=0.f, nrm=0.f;
    #pragma unroll
    for (int e=0;e<16;++e){ cost += ct_s[e]; nrm += nt_s[e]; }
    cost *= Wsum;
    float x = 9.75e-4f*(beta_a[o] - cost);  // inv_temp iter1 = 0.01*(1-0.95^2)
    float aj = 1.f/(1.f + __expf(-x));
    scale_s = aj/(sqrtf(nrm) + EPSF);
  }
  __syncthreads();
  if (t < 16){
    out[(size_t)bo*ND + t] = scale_s*mean_s[t];   // fp32 store
  }
}

// ---------------- host ------------------------------------------------------
extern "C" void kernel_launch(void* const* d_in, const int* in_sizes, int n_in,
                              void* d_out, int out_size, void* d_ws, size_t ws_size,
                              hipStream_t stream)
{
  const float* u      = (const float*)d_in[0];
  const float* W      = (const float*)d_in[1];
  const float* beta_a = (const float*)d_in[2];
  const float* beta_u = (const float*)d_in[3];
  const float* bias   = (const float*)d_in[4];
  float* ws  = (float*)d_ws;
  float* out = (float*)d_out;

  const size_t base_f = (size_t)NB*NI + NB + 2u*NB*NO*ND + NB*NO;   // 208,960 floats
  const size_t per_ch = 2u*(size_t)NB*NO*ND + (size_t)NB*NO;       // 135,168 floats/chunk
  int CH = 2;
  if      (ws_size >= (base_f + per_ch*32)*4) CH = 32;
  else if (ws_size >= (base_f + per_ch*8 )*4) CH = 8;

  float* a_i  = ws;
  float* asum = a_i  + NB*NI;
  float* mean0= asum + NB;
  float* i2v0 = mean0 + (size_t)NB*NO*ND;
  float* c0   = i2v0 + (size_t)NB*NO*ND;
  float* S1p  = c0   + (size_t)NB*NO;
  float* S2p  = S1p  + (size_t)NB*CH*NO*ND;
  float* Wsp  = S2p  + (size_t)NB*CH*NO*ND;

  k_ai<<<NB, 256, 0, stream>>>(u, a_i, asum);
  k_mstep0<<<dim3(NO, 8), 256, 0, stream>>>(u, W, beta_a, beta_u, bias, a_i, asum,
                                            mean0, i2v0, c0);
  k_estep1<<<dim3(NB/4, CH), 256, 0, stream>>>(u, W, bias, a_i, mean0, i2v0, c0,
                                               S1p, S2p, Wsp);
  k_final<<<NB*NO, 64, 0, stream>>>(beta_a, beta_u, S1p, S2p, Wsp, CH, out);
}